// Round 7
// baseline (45.284 us; speedup 1.0000x reference)
//
#include <hip/hip_runtime.h>
#include <math.h>

// SpectralCompactnessLoss: B=2, C=32, K=2, N=H*W*D=393216 voxels per batch.
// THREE dispatches, NO device-scope fences, NO cross-block tickets
// (round-4 lesson: per-block __threadfence() -> L2 writeback/inv storm, 6x regression).
//   pass1: channel-split masked sums -> part[4096], cntPart[64]   (FULL unroll, 12 iters)
//   pass2: in-block center reduce (coalesced, L3-hot) + float4 weighted distance (unroll 16)
//   pass3: tiny final reduce -> out[0]
#define CCH 32
#define KCLS 2
#define BB 2
#define SSEG 32
#define NVOX 393216
#define SEGITERS ((NVOX / SSEG) / 4 / 256)  // 12
#define P1_BLOCKS (BB * SSEG * CCH)         // 2048
#define P2_PER_B 384
#define P2_BLOCKS (BB * P2_PER_B)           // 768
#define PART_PER_B (SSEG * CCH * 2)         // 2048 floats = 8 KB

// ws float offsets
#define OFF_PART 0                            // 4096
#define OFF_CNTP (OFF_PART + P1_BLOCKS * 2)   // 64
#define OFF_LOSS (OFF_CNTP + BB * SSEG)       // 1536

__device__ __forceinline__ float waveReduceSum(float v) {
#pragma unroll
    for (int o = 32; o > 0; o >>= 1) v += __shfl_down(v, o);
    return v;
}

// Pass 1: block = (b, s, c); streams one channel-row segment.
__global__ void __launch_bounds__(256) scl_pass1(
    const float* __restrict__ feat, const int* __restrict__ tgt,
    float* __restrict__ part, float* __restrict__ cntPart, int N) {
    const int blk = blockIdx.x;
    const int c = blk & (CCH - 1);
    const int s = (blk >> 5) & (SSEG - 1);
    const int b = blk >> 10;
    const int segVox = NVOX / SSEG;           // 12288

    const float* fb = feat + ((size_t)(b * CCH + c)) * NVOX + (size_t)s * segVox;
    const int*   tb = tgt + (size_t)b * NVOX + (size_t)s * segVox;

    float s1 = 0.f, st = 0.f, c1 = 0.f;
    const int base = threadIdx.x;
#pragma unroll
    for (int it = 0; it < SEGITERS; ++it) {
        const int n = (base + it * 256) * 4;
        const int4   t4 = *reinterpret_cast<const int4*>(tb + n);
        const float4 v  = *reinterpret_cast<const float4*>(fb + n);
        const float m1x = t4.x ? 1.f : 0.f;
        const float m1y = t4.y ? 1.f : 0.f;
        const float m1z = t4.z ? 1.f : 0.f;
        const float m1w = t4.w ? 1.f : 0.f;
        st += (v.x + v.y) + (v.z + v.w);
        s1 += v.x * m1x + v.y * m1y + v.z * m1z + v.w * m1w;
        c1 += (m1x + m1y) + (m1z + m1w);
    }

    __shared__ float sm[4][3];
    const int lane = threadIdx.x & 63;
    const int wv   = threadIdx.x >> 6;
    float r1 = waveReduceSum(s1);
    float rt = waveReduceSum(st);
    float rc = waveReduceSum(c1);
    if (lane == 0) { sm[wv][0] = r1; sm[wv][1] = rt; sm[wv][2] = rc; }
    __syncthreads();
    if (threadIdx.x == 0) {
        part[blk * 2 + 0] = sm[0][0] + sm[1][0] + sm[2][0] + sm[3][0];
        part[blk * 2 + 1] = sm[0][1] + sm[1][1] + sm[2][1] + sm[3][1];
        if (c == 0)
            cntPart[b * SSEG + s] = sm[0][2] + sm[1][2] + sm[2][2] + sm[3][2];
    }
}

// Pass 2: fence-free in-block center reduce + float4 per-voxel weighted distance.
__global__ void __launch_bounds__(256) scl_pass2(
    const float* __restrict__ feat, const float* __restrict__ pred,
    const int* __restrict__ tgt,
    const float* __restrict__ part, const float* __restrict__ cntPart,
    float* __restrict__ lossPart, int N) {
    const int blk = blockIdx.x;
    const int b  = (blk >= P2_PER_B) ? 1 : 0;
    const int lb = blk - b * P2_PER_B;
    const int t = threadIdx.x;

    // ---- preamble: coalesced load of this b's partials, reduce to centers ----
    __shared__ float psm[PART_PER_B];   // 8 KB
    __shared__ float csm[SSEG];
    __shared__ float red[64];
    __shared__ float ctr[KCLS * CCH];
    __shared__ float c1sh;
    {
        const float* pb = part + b * PART_PER_B;
#pragma unroll
        for (int i = 0; i < PART_PER_B / 256; ++i)
            psm[t + i * 256] = pb[t + i * 256];
        if (t < SSEG) csm[t] = cntPart[b * SSEG + t];
    }
    __syncthreads();
    if (t < 64) {
        float s = 0.f;
#pragma unroll
        for (int ss = 0; ss < SSEG; ++ss) s += psm[ss * 64 + t];
        red[t] = s;
    } else if (t == 64) {
        float cx = 0.f;
#pragma unroll
        for (int ss = 0; ss < SSEG; ++ss) cx += csm[ss];
        c1sh = cx;
    }
    __syncthreads();
    if (t < CCH) {
        const float c1 = c1sh;
        const float c0 = (float)NVOX - c1;
        const float s1 = red[t * 2 + 0];
        const float st = red[t * 2 + 1];
        ctr[t]       = (st - s1) / fmaxf(c0, 1.f);
        ctr[CCH + t] = s1 / fmaxf(c1, 1.f);
    }
    __syncthreads();

    // ---- main: 4 voxels per thread (float4), deep unroll for MLP ----
    const int n = (lb * 256 + t) * 4;
    const float* fb = feat + (size_t)b * CCH * NVOX;
    const float* p0 = pred + (size_t)b * KCLS * NVOX;
    const float* p1 = p0 + NVOX;
    const int*   tb = tgt + (size_t)b * NVOX;

    const int4   t4 = *reinterpret_cast<const int4*>(tb + n);
    const float4 a0 = *reinterpret_cast<const float4*>(p0 + n);
    const float4 a1 = *reinterpret_cast<const float4*>(p1 + n);

    float d2x = 0.f, d2y = 0.f, d2z = 0.f, d2w = 0.f;
#pragma unroll 16
    for (int c = 0; c < CCH; ++c) {
        const float4 v = *reinterpret_cast<const float4*>(fb + (size_t)c * NVOX + n);
        const float c0 = ctr[c], c1 = ctr[CCH + c];
        float d;
        d = v.x - (t4.x ? c1 : c0); d2x += d * d;
        d = v.y - (t4.y ? c1 : c0); d2y += d * d;
        d = v.z - (t4.z ? c1 : c0); d2z += d * d;
        d = v.w - (t4.w ? c1 : c0); d2w += d * d;
    }

    // conf_own = 1 / (1 + exp(a_other - a_own))
    float l0 = 0.f, l1 = 0.f, z, cf, w;
    z = t4.x ? (a0.x - a1.x) : (a1.x - a0.x);
    cf = 1.f / (1.f + __expf(z));
    w = sqrtf(d2x) * cf; l0 += t4.x ? 0.f : w; l1 += t4.x ? w : 0.f;
    z = t4.y ? (a0.y - a1.y) : (a1.y - a0.y);
    cf = 1.f / (1.f + __expf(z));
    w = sqrtf(d2y) * cf; l0 += t4.y ? 0.f : w; l1 += t4.y ? w : 0.f;
    z = t4.z ? (a0.z - a1.z) : (a1.z - a0.z);
    cf = 1.f / (1.f + __expf(z));
    w = sqrtf(d2z) * cf; l0 += t4.z ? 0.f : w; l1 += t4.z ? w : 0.f;
    z = t4.w ? (a0.w - a1.w) : (a1.w - a0.w);
    cf = 1.f / (1.f + __expf(z));
    w = sqrtf(d2w) * cf; l0 += t4.w ? 0.f : w; l1 += t4.w ? w : 0.f;

    const int lane = t & 63;
    const int wv   = t >> 6;
    float r0 = waveReduceSum(l0);
    float r1 = waveReduceSum(l1);
    if (lane == 0) { red[wv * 2 + 0] = r0; red[wv * 2 + 1] = r1; }
    __syncthreads();
    if (t == 0) {
        lossPart[blk * 2 + 0] = (red[0] + red[2]) + (red[4] + red[6]);
        lossPart[blk * 2 + 1] = (red[1] + red[3]) + (red[5] + red[7]);
    }
}

// Pass 3: tiny final reduce. One block, 256 threads.
__global__ void __launch_bounds__(256) scl_pass3(
    const float* __restrict__ lossPart, const float* __restrict__ cntPart,
    float* __restrict__ out, int N) {
    const int t = threadIdx.x;
    float a00 = 0.f, a01 = 0.f, a10 = 0.f, a11 = 0.f;
    for (int i = t; i < P2_BLOCKS; i += 256) {
        const float e0 = lossPart[i * 2 + 0];
        const float e1 = lossPart[i * 2 + 1];
        if (i < P2_PER_B) { a00 += e0; a01 += e1; }
        else              { a10 += e0; a11 += e1; }
    }
    __shared__ float sm[4][4];
    const int lane = t & 63;
    const int wv   = t >> 6;
    float q0 = waveReduceSum(a00);
    float q1 = waveReduceSum(a01);
    float q2 = waveReduceSum(a10);
    float q3 = waveReduceSum(a11);
    if (lane == 0) { sm[wv][0] = q0; sm[wv][1] = q1; sm[wv][2] = q2; sm[wv][3] = q3; }
    __syncthreads();
    if (t == 0) {
        float loss[4];
#pragma unroll
        for (int i = 0; i < 4; ++i)
            loss[i] = (sm[0][i] + sm[1][i]) + (sm[2][i] + sm[3][i]);
        float c1b0 = 0.f, c1b1 = 0.f;
#pragma unroll
        for (int ss = 0; ss < SSEG; ++ss) {
            c1b0 += cntPart[ss];
            c1b1 += cntPart[SSEG + ss];
        }
        float cn[4];
        cn[0] = (float)NVOX - c1b0; cn[1] = c1b0;
        cn[2] = (float)NVOX - c1b1; cn[3] = c1b1;
        float total = 0.f, nv = 0.f;
#pragma unroll
        for (int bk = 0; bk < 4; ++bk) {
            if (cn[bk] >= 2.f) { total += loss[bk] / fmaxf(cn[bk], 1.f); nv += 1.f; }
        }
        out[0] = (nv > 0.f) ? (total / nv) : 0.f;
    }
}

extern "C" void kernel_launch(void* const* d_in, const int* in_sizes, int n_in,
                              void* d_out, int out_size, void* d_ws, size_t ws_size,
                              hipStream_t stream) {
    const float* feat = (const float*)d_in[0];
    const float* pred = (const float*)d_in[1];
    const int*   tgt  = (const int*)d_in[2];
    float* out = (float*)d_out;

    const int totalVox = in_sizes[2];   // B*N
    const int N = totalVox / BB;        // 393216

    float* ws       = (float*)d_ws;
    float* part     = ws + OFF_PART;
    float* cntPart  = ws + OFF_CNTP;
    float* lossPart = ws + OFF_LOSS;

    scl_pass1<<<P1_BLOCKS, 256, 0, stream>>>(feat, tgt, part, cntPart, N);
    scl_pass2<<<P2_BLOCKS, 256, 0, stream>>>(feat, pred, tgt, part, cntPart,
                                             lossPart, N);
    scl_pass3<<<1, 256, 0, stream>>>(lossPart, cntPart, out, N);
}

// Round 8
// 44.326 us; speedup vs baseline: 1.0216x; 1.0216x over previous
//
#include <hip/hip_runtime.h>
#include <math.h>

// SpectralCompactnessLoss: B=2, C=32, K=2, N=H*W*D=393216 voxels per batch.
// THREE dispatches, NO device-scope fences, NO cross-block tickets
// (round-4 lesson: per-block __threadfence() -> L2 writeback/inv storm, 6x regression).
//   pass1: channel-split masked sums -> part[4096], cntPart[64]   (unroll 3 = round-6 best)
//   pass2: issue main loads FIRST (tgt/pred/8 feat channels into regs), THEN reduce
//          centers from part[] (register-accum, no LDS staging) -> preamble latency
//          hides under the main loads' HBM latency (T14 issue-early pattern).
//   pass3: tiny final reduce -> out[0]
#define CCH 32
#define KCLS 2
#define BB 2
#define SSEG 32
#define NVOX 393216
#define SEGITERS ((NVOX / SSEG) / 4 / 256)  // 12
#define P1_BLOCKS (BB * SSEG * CCH)         // 2048
#define P2_PER_B 384
#define P2_BLOCKS (BB * P2_PER_B)           // 768
#define PART_PER_B (SSEG * CCH * 2)         // 2048 floats = 8 KB
#define NPRE 8                              // feat channels preloaded before preamble

// ws float offsets
#define OFF_PART 0                            // 4096
#define OFF_CNTP (OFF_PART + P1_BLOCKS * 2)   // 64
#define OFF_LOSS (OFF_CNTP + BB * SSEG)       // 1536

__device__ __forceinline__ float waveReduceSum(float v) {
#pragma unroll
    for (int o = 32; o > 0; o >>= 1) v += __shfl_down(v, o);
    return v;
}

// Pass 1: block = (b, s, c); streams one channel-row segment. (round-6 measured best)
__global__ void __launch_bounds__(256) scl_pass1(
    const float* __restrict__ feat, const int* __restrict__ tgt,
    float* __restrict__ part, float* __restrict__ cntPart, int N) {
    const int blk = blockIdx.x;
    const int c = blk & (CCH - 1);
    const int s = (blk >> 5) & (SSEG - 1);
    const int b = blk >> 10;
    const int segVox = NVOX / SSEG;           // 12288

    const float* fb = feat + ((size_t)(b * CCH + c)) * NVOX + (size_t)s * segVox;
    const int*   tb = tgt + (size_t)b * NVOX + (size_t)s * segVox;

    float s1 = 0.f, st = 0.f, c1 = 0.f;
    const int base = threadIdx.x;
#pragma unroll 3
    for (int it = 0; it < SEGITERS; ++it) {
        const int n = (base + it * 256) * 4;
        const int4   t4 = *reinterpret_cast<const int4*>(tb + n);
        const float4 v  = *reinterpret_cast<const float4*>(fb + n);
        const float m1x = t4.x ? 1.f : 0.f;
        const float m1y = t4.y ? 1.f : 0.f;
        const float m1z = t4.z ? 1.f : 0.f;
        const float m1w = t4.w ? 1.f : 0.f;
        st += (v.x + v.y) + (v.z + v.w);
        s1 += v.x * m1x + v.y * m1y + v.z * m1z + v.w * m1w;
        c1 += (m1x + m1y) + (m1z + m1w);
    }

    __shared__ float sm[4][3];
    const int lane = threadIdx.x & 63;
    const int wv   = threadIdx.x >> 6;
    float r1 = waveReduceSum(s1);
    float rt = waveReduceSum(st);
    float rc = waveReduceSum(c1);
    if (lane == 0) { sm[wv][0] = r1; sm[wv][1] = rt; sm[wv][2] = rc; }
    __syncthreads();
    if (threadIdx.x == 0) {
        part[blk * 2 + 0] = sm[0][0] + sm[1][0] + sm[2][0] + sm[3][0];
        part[blk * 2 + 1] = sm[0][1] + sm[1][1] + sm[2][1] + sm[3][1];
        if (c == 0)
            cntPart[b * SSEG + s] = sm[0][2] + sm[1][2] + sm[2][2] + sm[3][2];
    }
}

// Pass 2: issue-early main loads + register-accum center reduce + weighted distance.
__global__ void __launch_bounds__(256) scl_pass2(
    const float* __restrict__ feat, const float* __restrict__ pred,
    const int* __restrict__ tgt,
    const float* __restrict__ part, const float* __restrict__ cntPart,
    float* __restrict__ lossPart, int N) {
    const int blk = blockIdx.x;
    const int b  = (blk >= P2_PER_B) ? 1 : 0;
    const int lb = blk - b * P2_PER_B;
    const int t = threadIdx.x;

    const int n = (lb * 256 + t) * 4;
    const float* fb = feat + (size_t)b * CCH * NVOX;
    const float* p0 = pred + (size_t)b * KCLS * NVOX;
    const float* p1 = p0 + NVOX;
    const int*   tb = tgt + (size_t)b * NVOX;

    // ---- issue main loads FIRST (independent of centers) ----
    const int4   t4 = *reinterpret_cast<const int4*>(tb + n);
    const float4 a0 = *reinterpret_cast<const float4*>(p0 + n);
    const float4 a1 = *reinterpret_cast<const float4*>(p1 + n);
    float4 f[NPRE];
#pragma unroll
    for (int i = 0; i < NPRE; ++i)
        f[i] = *reinterpret_cast<const float4*>(fb + (size_t)i * NVOX + n);

    // ---- preamble: center reduce, register-accum (no LDS staging) ----
    __shared__ float red4[4][64];
    __shared__ float ctr[KCLS * CCH];
    __shared__ float c1sh;
    {
        const float* pb = part + b * PART_PER_B;
        const int cv = t & 63, sg = t >> 6;
        float pacc = 0.f;
#pragma unroll
        for (int j = 0; j < 8; ++j)
            pacc += pb[(sg * 8 + j) * 64 + cv];
        red4[sg][cv] = pacc;
        float cacc = (t < SSEG) ? cntPart[b * SSEG + t] : 0.f;
        float wr = waveReduceSum(cacc);    // meaningful only in wave 0
        if (t == 0) c1sh = wr;
    }
    __syncthreads();
    if (t < CCH) {
        const float c1 = c1sh;
        const float c0 = (float)NVOX - c1;
        const float s1 = (red4[0][t * 2]     + red4[1][t * 2])
                       + (red4[2][t * 2]     + red4[3][t * 2]);
        const float st = (red4[0][t * 2 + 1] + red4[1][t * 2 + 1])
                       + (red4[2][t * 2 + 1] + red4[3][t * 2 + 1]);
        ctr[t]       = (st - s1) / fmaxf(c0, 1.f);
        ctr[CCH + t] = s1 / fmaxf(c1, 1.f);
    }
    __syncthreads();

    // ---- main: consume preloaded channels, then stream the rest ----
    float d2x = 0.f, d2y = 0.f, d2z = 0.f, d2w = 0.f;
#pragma unroll
    for (int c = 0; c < NPRE; ++c) {
        const float4 v = f[c];
        const float c0 = ctr[c], c1 = ctr[CCH + c];
        float d;
        d = v.x - (t4.x ? c1 : c0); d2x += d * d;
        d = v.y - (t4.y ? c1 : c0); d2y += d * d;
        d = v.z - (t4.z ? c1 : c0); d2z += d * d;
        d = v.w - (t4.w ? c1 : c0); d2w += d * d;
    }
#pragma unroll 8
    for (int c = NPRE; c < CCH; ++c) {
        const float4 v = *reinterpret_cast<const float4*>(fb + (size_t)c * NVOX + n);
        const float c0 = ctr[c], c1 = ctr[CCH + c];
        float d;
        d = v.x - (t4.x ? c1 : c0); d2x += d * d;
        d = v.y - (t4.y ? c1 : c0); d2y += d * d;
        d = v.z - (t4.z ? c1 : c0); d2z += d * d;
        d = v.w - (t4.w ? c1 : c0); d2w += d * d;
    }

    // conf_own = 1 / (1 + exp(a_other - a_own))
    float l0 = 0.f, l1 = 0.f, z, cf, w;
    z = t4.x ? (a0.x - a1.x) : (a1.x - a0.x);
    cf = 1.f / (1.f + __expf(z));
    w = sqrtf(d2x) * cf; l0 += t4.x ? 0.f : w; l1 += t4.x ? w : 0.f;
    z = t4.y ? (a0.y - a1.y) : (a1.y - a0.y);
    cf = 1.f / (1.f + __expf(z));
    w = sqrtf(d2y) * cf; l0 += t4.y ? 0.f : w; l1 += t4.y ? w : 0.f;
    z = t4.z ? (a0.z - a1.z) : (a1.z - a0.z);
    cf = 1.f / (1.f + __expf(z));
    w = sqrtf(d2z) * cf; l0 += t4.z ? 0.f : w; l1 += t4.z ? w : 0.f;
    z = t4.w ? (a0.w - a1.w) : (a1.w - a0.w);
    cf = 1.f / (1.f + __expf(z));
    w = sqrtf(d2w) * cf; l0 += t4.w ? 0.f : w; l1 += t4.w ? w : 0.f;

    const int lane = t & 63;
    const int wv   = t >> 6;
    float r0 = waveReduceSum(l0);
    float r1 = waveReduceSum(l1);
    __syncthreads();   // red4 reuse
    if (lane == 0) { red4[wv][0] = r0; red4[wv][1] = r1; }
    __syncthreads();
    if (t == 0) {
        lossPart[blk * 2 + 0] = (red4[0][0] + red4[1][0]) + (red4[2][0] + red4[3][0]);
        lossPart[blk * 2 + 1] = (red4[0][1] + red4[1][1]) + (red4[2][1] + red4[3][1]);
    }
}

// Pass 3: tiny final reduce. One block, 256 threads.
__global__ void __launch_bounds__(256) scl_pass3(
    const float* __restrict__ lossPart, const float* __restrict__ cntPart,
    float* __restrict__ out, int N) {
    const int t = threadIdx.x;
    float a00 = 0.f, a01 = 0.f, a10 = 0.f, a11 = 0.f;
    for (int i = t; i < P2_BLOCKS; i += 256) {
        const float e0 = lossPart[i * 2 + 0];
        const float e1 = lossPart[i * 2 + 1];
        if (i < P2_PER_B) { a00 += e0; a01 += e1; }
        else              { a10 += e0; a11 += e1; }
    }
    __shared__ float sm[4][4];
    const int lane = t & 63;
    const int wv   = t >> 6;
    float q0 = waveReduceSum(a00);
    float q1 = waveReduceSum(a01);
    float q2 = waveReduceSum(a10);
    float q3 = waveReduceSum(a11);
    if (lane == 0) { sm[wv][0] = q0; sm[wv][1] = q1; sm[wv][2] = q2; sm[wv][3] = q3; }
    __syncthreads();
    if (t == 0) {
        float loss[4];
#pragma unroll
        for (int i = 0; i < 4; ++i)
            loss[i] = (sm[0][i] + sm[1][i]) + (sm[2][i] + sm[3][i]);
        float c1b0 = 0.f, c1b1 = 0.f;
#pragma unroll
        for (int ss = 0; ss < SSEG; ++ss) {
            c1b0 += cntPart[ss];
            c1b1 += cntPart[SSEG + ss];
        }
        float cn[4];
        cn[0] = (float)NVOX - c1b0; cn[1] = c1b0;
        cn[2] = (float)NVOX - c1b1; cn[3] = c1b1;
        float total = 0.f, nv = 0.f;
#pragma unroll
        for (int bk = 0; bk < 4; ++bk) {
            if (cn[bk] >= 2.f) { total += loss[bk] / fmaxf(cn[bk], 1.f); nv += 1.f; }
        }
        out[0] = (nv > 0.f) ? (total / nv) : 0.f;
    }
}

extern "C" void kernel_launch(void* const* d_in, const int* in_sizes, int n_in,
                              void* d_out, int out_size, void* d_ws, size_t ws_size,
                              hipStream_t stream) {
    const float* feat = (const float*)d_in[0];
    const float* pred = (const float*)d_in[1];
    const int*   tgt  = (const int*)d_in[2];
    float* out = (float*)d_out;

    const int totalVox = in_sizes[2];   // B*N
    const int N = totalVox / BB;        // 393216

    float* ws       = (float*)d_ws;
    float* part     = ws + OFF_PART;
    float* cntPart  = ws + OFF_CNTP;
    float* lossPart = ws + OFF_LOSS;

    scl_pass1<<<P1_BLOCKS, 256, 0, stream>>>(feat, tgt, part, cntPart, N);
    scl_pass2<<<P2_BLOCKS, 256, 0, stream>>>(feat, pred, tgt, part, cntPart,
                                             lossPart, N);
    scl_pass3<<<1, 256, 0, stream>>>(lossPart, cntPart, out, N);
}